// Round 1
// baseline (387.983 us; speedup 1.0000x reference)
//
#include <hip/hip_runtime.h>
#include <hip/hip_bf16.h>
#include <math.h>

#define T_LEN 4096
#define BATCH 16

// ---------------------------------------------------------------------------
// k_gcn: adapter + node projections + A_HAT propagation + relu + node-mean.
// (unchanged from R8)
// ---------------------------------------------------------------------------
__global__ __launch_bounds__(256) void k_gcn(
    const float* __restrict__ x,      // [B][T][218]
    const float* __restrict__ gcn_w,  // [18][64]
    float* __restrict__ hp)           // [B][64][T]
{
    __shared__ float xt[218 * 36];
    __shared__ float wg[18 * 64];

    const int b   = blockIdx.y;
    const int t0  = blockIdx.x * 32;
    const int tid = threadIdx.x;

    const float* xb = x + ((long)b * T_LEN + t0) * 218;
    #pragma unroll 1
    for (int i = tid; i < 32 * 218; i += 256) {
        const int t = i / 218;
        const int c = i - 218 * t;
        xt[c * 36 + t] = xb[i];
    }
    for (int i = tid; i < 18 * 64; i += 256) wg[i] = gcn_w[i];
    __syncthreads();

    const int dg = tid >> 4;
    const int tt = tid & 15;
    const int d0 = dg * 4;
    const int tb = tt * 2;

    float wr[10][4];
    #pragma unroll
    for (int c = 0; c < 10; ++c)
        *(float4*)wr[c] = *(const float4*)(gcn_w + c * 64 + d0);

    const float cP = 1.0f / 6.0f;
    const float cS = 0.23570226039551584f;   // 1/sqrt(18)
    const float c3 = 1.0f / 3.0f;
    const float cT = 0.4082482904638631f;    // 1/sqrt(6)
    const float cH = 0.5f;

    float h0[4][2];
    #pragma unroll
    for (int di = 0; di < 4; ++di) h0[di][0] = h0[di][1] = 0.f;
    #pragma unroll 1
    for (int c = 0; c < 18; ++c) {
        float wv[4];
        *(float4*)wv = *(const float4*)(&wg[c * 64 + d0]);
        const float2 xv = *(const float2*)(&xt[c * 36 + tb]);
        #pragma unroll
        for (int di = 0; di < 4; ++di) {
            h0[di][0] = fmaf(wv[di], xv.x, h0[di][0]);
            h0[di][1] = fmaf(wv[di], xv.y, h0[di][1]);
        }
    }

    float pool[4][2], star[4][2];
    #pragma unroll
    for (int di = 0; di < 4; ++di) {
        pool[di][0] = pool[di][1] = 0.f;
        star[di][0] = star[di][1] = 0.f;
    }

    #pragma unroll 1
    for (int f = 0; f < 5; ++f) {
        float hn[4][2], hprev[4][2], s12[4][2];
        #pragma unroll
        for (int n = 0; n < 4; ++n) {
            #pragma unroll
            for (int di = 0; di < 4; ++di) hn[di][0] = hn[di][1] = 0.f;
            const int cb = 18 + 10 * (4 * f + n);
            #pragma unroll
            for (int c = 0; c < 10; ++c) {
                const float2 xv = *(const float2*)(&xt[(cb + c) * 36 + tb]);
                #pragma unroll
                for (int di = 0; di < 4; ++di) {
                    hn[di][0] = fmaf(wr[c][di], xv.x, hn[di][0]);
                    hn[di][1] = fmaf(wr[c][di], xv.y, hn[di][1]);
                }
            }
            #pragma unroll
            for (int di = 0; di < 4; ++di)
                #pragma unroll
                for (int ti = 0; ti < 2; ++ti) {
                    const float h = hn[di][ti];
                    if (n == 0) {
                        star[di][ti] += h;
                        s12[di][ti] = h;
                        hprev[di][ti] = h;
                    } else if (n == 1) {
                        const float pa = fmaf(cS, h0[di][ti], c3 * (s12[di][ti] + h));
                        pool[di][ti] += fmaxf(pa, 0.f);
                        s12[di][ti] += h;
                        hprev[di][ti] = h;
                    } else if (n == 2) {
                        const float pb = c3 * (s12[di][ti] + h);
                        pool[di][ti] += fmaxf(pb, 0.f);
                        s12[di][ti] = hprev[di][ti] + h;
                        hprev[di][ti] = h;
                    } else {
                        const float pc = fmaf(cT, h, c3 * s12[di][ti]);
                        const float pe = fmaf(cT, hprev[di][ti], cH * h);
                        pool[di][ti] += fmaxf(pc, 0.f) + fmaxf(pe, 0.f);
                    }
                }
        }
    }

    float* hpb = hp + (long)b * 64 * T_LEN + t0 + tb;
    #pragma unroll
    for (int di = 0; di < 4; ++di) {
        float2 r;
        const float p0a = fmaf(cP, h0[di][0], cS * star[di][0]);
        const float p0b = fmaf(cP, h0[di][1], cS * star[di][1]);
        r.x = (pool[di][0] + fmaxf(p0a, 0.f)) * (1.0f / 21.0f);
        r.y = (pool[di][1] + fmaxf(p0b, 0.f)) * (1.0f / 21.0f);
        *(float2*)(hpb + (long)(d0 + di) * T_LEN) = r;
    }
}

// ---------------------------------------------------------------------------
// k_mstcn: one full MSTCN, fused, composite-uniform threads.
// R9: occupancy fix. Old config was 128 thr/block -> grid 1024 blocks =
// 4 blocks/CU x 2 waves = 8 waves/CU (20% occ) -> latency-bound
// (VALUBusy 37%, HBM 1.6%). New: block 256 = 16 cjg x 16 tt; same
// t-tile 64 and same 25.6 KB LDS, but each thread owns HALF the
// channels (1 s + 1 m + 2 l  x 4 t). Same grid -> 4 blocks/CU x 4
// waves = 16 waves/CU (50% occ), and VGPR pressure drops (weights
// 52->26 regs, acc 32->16). Window read stays 9x ds_read_b128,
// 16B-aligned, 4-way-broadcast conflict-free.
// ---------------------------------------------------------------------------
template <bool FINAL>
__global__ __launch_bounds__(256, 4) void k_mstcn(
    const float* __restrict__ in,   // [B][64][T]
    const float* __restrict__ ws, const float* __restrict__ bs,
    const float* __restrict__ wm, const float* __restrict__ bm,
    const float* __restrict__ wl, const float* __restrict__ bl,
    const float* __restrict__ wo, const float* __restrict__ bo,
    float* __restrict__ out,        // [B][64][T]  (FINAL=false)
    const float* __restrict__ wd,   // [64][32]    (FINAL=true)
    const float* __restrict__ bd,   // [32]
    float* __restrict__ outp)       // [B][32]     (FINAL=true)
{
    __shared__ float smem[64 * 100]; // x-tile [c][96] stride 100; h aliased

    const int b   = blockIdx.y;
    const int t0  = blockIdx.x * 64;
    const int tid = threadIdx.x;
    const int cjg = tid >> 4;        // 0..15 composite j-group
    const int tt  = tid & 15;        // 4 t at tt*4

    // ---- stage x window [t0-32, t0+64) as [c][96], stride 100 ----
    const float* inb = in + (long)b * 64 * T_LEN;
    #pragma unroll 1
    for (int i = tid; i < 64 * 24; i += 256) {
        const int c = i / 24;
        const int q = i - c * 24;
        const int t = t0 - 32 + q * 4;
        float4 v = make_float4(0.f, 0.f, 0.f, 0.f);
        if (t >= 0) v = *(const float4*)(inb + (long)c * T_LEN + t);
        *(float4*)(&smem[c * 100 + q * 4]) = v;
    }
    __syncthreads();

    // ---- conv phase ----
    const int js = cjg;              // 1 s channel  (concat 0..15)
    const int jm = cjg;              // 1 m channel  (concat 16..31)
    const int jl = 2 * cjg;          // 2 l channels (concat 32..63)

    float as[4], am[4], al[2][4];
    {
        const float b1s = bs[js];
        const float b1m = bm[jm];
        const float2 b2l = *(const float2*)(bl + jl);
        #pragma unroll
        for (int i = 0; i < 4; ++i) {
            as[i] = b1s; am[i] = b1m;
            al[0][i] = b2l.x; al[1][i] = b2l.y;
        }
    }

    float  wsr[3], wmr[5];
    float2 wlr[9];
    #pragma unroll
    for (int k = 0; k < 3; ++k) wsr[k] = ws[(k * 64) * 16 + js];
    #pragma unroll
    for (int k = 0; k < 5; ++k) wmr[k] = wm[(k * 64) * 16 + jm];
    #pragma unroll
    for (int k = 0; k < 9; ++k) wlr[k] = *(const float2*)(wl + (k * 64) * 32 + jl);

    #pragma unroll 1
    for (int c = 0; c < 64; ++c) {
        // window: tile cols tt*4 .. tt*4+35  (covers t-32 .. t+3)
        float win[36];
        {
            const float* rb = &smem[c * 100 + tt * 4];
            #pragma unroll
            for (int m = 0; m < 9; ++m)
                *(float4*)(&win[4 * m]) = *(const float4*)(rb + 4 * m);
        }
        const int cn = (c < 63) ? c + 1 : 63;

        // conv_s: x[t-2+k] -> win[30+i+k]
        #pragma unroll
        for (int k = 0; k < 3; ++k) {
            #pragma unroll
            for (int i = 0; i < 4; ++i)
                as[i] = fmaf(wsr[k], win[30 + i + k], as[i]);
            wsr[k] = ws[(k * 64 + cn) * 16 + js];
        }
        // conv_m: x[t-8+2k] -> win[24+i+2k]
        #pragma unroll
        for (int k = 0; k < 5; ++k) {
            #pragma unroll
            for (int i = 0; i < 4; ++i)
                am[i] = fmaf(wmr[k], win[24 + i + 2 * k], am[i]);
            wmr[k] = wm[(k * 64 + cn) * 16 + jm];
        }
        // conv_l: x[t-32+4k] -> win[i+4k]
        #pragma unroll
        for (int k = 0; k < 9; ++k) {
            #pragma unroll
            for (int i = 0; i < 4; ++i) {
                const float v = win[i + 4 * k];
                al[0][i] = fmaf(wlr[k].x, v, al[0][i]);
                al[1][i] = fmaf(wlr[k].y, v, al[1][i]);
            }
            wlr[k] = *(const float2*)(wl + (k * 64 + cn) * 32 + jl);
        }
    }

    // ---- relu + stage h [64 j][64 t] stride 68 (aliased) ----
    __syncthreads();
    *(float4*)(&smem[js * 68 + tt * 4]) =
        make_float4(fmaxf(as[0], 0.f), fmaxf(as[1], 0.f),
                    fmaxf(as[2], 0.f), fmaxf(as[3], 0.f));
    *(float4*)(&smem[(16 + jm) * 68 + tt * 4]) =
        make_float4(fmaxf(am[0], 0.f), fmaxf(am[1], 0.f),
                    fmaxf(am[2], 0.f), fmaxf(am[3], 0.f));
    #pragma unroll
    for (int j = 0; j < 2; ++j)
        *(float4*)(&smem[(32 + jl + j) * 68 + tt * 4]) =
            make_float4(fmaxf(al[j][0], 0.f), fmaxf(al[j][1], 0.f),
                        fmaxf(al[j][2], 0.f), fmaxf(al[j][3], 0.f));
    __syncthreads();

    // ---- conv_out 64->64 (no relu): thread = 4 d x 4 t ----
    const int d0 = cjg * 4;
    float o[4][4];
    {
        float bv[4];
        *(float4*)bv = *(const float4*)(bo + d0);
        #pragma unroll
        for (int di = 0; di < 4; ++di)
            #pragma unroll
            for (int i = 0; i < 4; ++i) o[di][i] = bv[di];
    }
    #pragma unroll 4
    for (int j = 0; j < 64; ++j) {
        float wv[4], hv[4];
        *(float4*)wv = *(const float4*)(wo + j * 64 + d0);
        *(float4*)hv = *(const float4*)(&smem[j * 68 + tt * 4]);
        #pragma unroll
        for (int di = 0; di < 4; ++di)
            #pragma unroll
            for (int i = 0; i < 4; ++i)
                o[di][i] = fmaf(wv[di], hv[i], o[di][i]);
    }

    if (!FINAL) {
        float* ob = out + (long)b * 64 * T_LEN + t0 + tt * 4;
        #pragma unroll
        for (int di = 0; di < 4; ++di)
            *(float4*)(ob + (long)(d0 + di) * T_LEN) =
                make_float4(o[di][0], o[di][1], o[di][2], o[di][3]);
    } else {
        // ---- stage t2 [64 d][64 t], then dense 64->32 + tanh + mean ----
        __syncthreads();
        #pragma unroll
        for (int di = 0; di < 4; ++di)
            *(float4*)(&smem[(d0 + di) * 68 + tt * 4]) =
                make_float4(o[di][0], o[di][1], o[di][2], o[di][3]);
        __syncthreads();

        const int eg = tid >> 5;       // 8 groups x 4 e
        const int e0 = eg * 4;
        const int tl = tid & 31;       // 2 t at tl*2
        float fa[4], fb[4];
        *(float4*)fa = *(const float4*)(bd + e0);
        #pragma unroll
        for (int e = 0; e < 4; ++e) fb[e] = fa[e];

        #pragma unroll 4
        for (int d = 0; d < 64; ++d) {
            const float2 hv = *(const float2*)(&smem[d * 68 + tl * 2]);
            float wv[4];
            *(float4*)wv = *(const float4*)(wd + d * 32 + e0);
            #pragma unroll
            for (int e = 0; e < 4; ++e) {
                fa[e] = fmaf(wv[e], hv.x, fa[e]);
                fb[e] = fmaf(wv[e], hv.y, fb[e]);
            }
        }
        #pragma unroll
        for (int e = 0; e < 4; ++e) {
            float v = (tanhf(fa[e]) + tanhf(fb[e])) * (1.0f / (float)T_LEN);
            v += __shfl_down(v, 16, 32);
            v += __shfl_down(v, 8, 32);
            v += __shfl_down(v, 4, 32);
            v += __shfl_down(v, 2, 32);
            v += __shfl_down(v, 1, 32);
            if (tl == 0) atomicAdd(&outp[b * 32 + e0 + e], v);
        }
    }
}

extern "C" void kernel_launch(void* const* d_in, const int* in_sizes, int n_in,
                              void* d_out, int out_size, void* d_ws, size_t ws_size,
                              hipStream_t stream) {
    const float* x     = (const float*)d_in[0];
    const float* gcn_w = (const float*)d_in[1];
    const float* wd    = (const float*)d_in[2];
    const float* bd    = (const float*)d_in[3];
    const float* t1_ws = (const float*)d_in[4];
    const float* t1_bs = (const float*)d_in[5];
    const float* t1_wm = (const float*)d_in[6];
    const float* t1_bm = (const float*)d_in[7];
    const float* t1_wl = (const float*)d_in[8];
    const float* t1_bl = (const float*)d_in[9];
    const float* t1_wo = (const float*)d_in[10];
    const float* t1_bo = (const float*)d_in[11];
    const float* t2_ws = (const float*)d_in[12];
    const float* t2_bs = (const float*)d_in[13];
    const float* t2_wm = (const float*)d_in[14];
    const float* t2_bm = (const float*)d_in[15];
    const float* t2_wl = (const float*)d_in[16];
    const float* t2_bl = (const float*)d_in[17];
    const float* t2_wo = (const float*)d_in[18];
    const float* t2_bo = (const float*)d_in[19];

    float* b0 = (float*)d_ws;                          // [16][64][4096]
    float* b1 = b0 + (size_t)BATCH * 64 * T_LEN;       // [16][64][4096]

    hipMemsetAsync(d_out, 0, (size_t)out_size * sizeof(float), stream);

    k_gcn<<<dim3(T_LEN / 32, BATCH), 256, 0, stream>>>(x, gcn_w, b0);

    k_mstcn<false><<<dim3(T_LEN / 64, BATCH), 256, 0, stream>>>(
        b0, t1_ws, t1_bs, t1_wm, t1_bm, t1_wl, t1_bl, t1_wo, t1_bo,
        b1, nullptr, nullptr, nullptr);

    k_mstcn<true><<<dim3(T_LEN / 64, BATCH), 256, 0, stream>>>(
        b1, t2_ws, t2_bs, t2_wm, t2_bm, t2_wl, t2_bl, t2_wo, t2_bo,
        nullptr, wd, bd, (float*)d_out);
}

// Round 2
// 364.730 us; speedup vs baseline: 1.0638x; 1.0638x over previous
//
#include <hip/hip_runtime.h>
#include <hip/hip_bf16.h>
#include <math.h>

#define T_LEN 4096
#define BATCH 16

// ---------------------------------------------------------------------------
// k_gcn: adapter + node projections + A_HAT propagation + relu + node-mean.
// (unchanged from R8)
// ---------------------------------------------------------------------------
__global__ __launch_bounds__(256) void k_gcn(
    const float* __restrict__ x,      // [B][T][218]
    const float* __restrict__ gcn_w,  // [18][64]
    float* __restrict__ hp)           // [B][64][T]
{
    __shared__ float xt[218 * 36];
    __shared__ float wg[18 * 64];

    const int b   = blockIdx.y;
    const int t0  = blockIdx.x * 32;
    const int tid = threadIdx.x;

    const float* xb = x + ((long)b * T_LEN + t0) * 218;
    #pragma unroll 1
    for (int i = tid; i < 32 * 218; i += 256) {
        const int t = i / 218;
        const int c = i - 218 * t;
        xt[c * 36 + t] = xb[i];
    }
    for (int i = tid; i < 18 * 64; i += 256) wg[i] = gcn_w[i];
    __syncthreads();

    const int dg = tid >> 4;
    const int tt = tid & 15;
    const int d0 = dg * 4;
    const int tb = tt * 2;

    float wr[10][4];
    #pragma unroll
    for (int c = 0; c < 10; ++c)
        *(float4*)wr[c] = *(const float4*)(gcn_w + c * 64 + d0);

    const float cP = 1.0f / 6.0f;
    const float cS = 0.23570226039551584f;   // 1/sqrt(18)
    const float c3 = 1.0f / 3.0f;
    const float cT = 0.4082482904638631f;    // 1/sqrt(6)
    const float cH = 0.5f;

    float h0[4][2];
    #pragma unroll
    for (int di = 0; di < 4; ++di) h0[di][0] = h0[di][1] = 0.f;
    #pragma unroll 1
    for (int c = 0; c < 18; ++c) {
        float wv[4];
        *(float4*)wv = *(const float4*)(&wg[c * 64 + d0]);
        const float2 xv = *(const float2*)(&xt[c * 36 + tb]);
        #pragma unroll
        for (int di = 0; di < 4; ++di) {
            h0[di][0] = fmaf(wv[di], xv.x, h0[di][0]);
            h0[di][1] = fmaf(wv[di], xv.y, h0[di][1]);
        }
    }

    float pool[4][2], star[4][2];
    #pragma unroll
    for (int di = 0; di < 4; ++di) {
        pool[di][0] = pool[di][1] = 0.f;
        star[di][0] = star[di][1] = 0.f;
    }

    #pragma unroll 1
    for (int f = 0; f < 5; ++f) {
        float hn[4][2], hprev[4][2], s12[4][2];
        #pragma unroll
        for (int n = 0; n < 4; ++n) {
            #pragma unroll
            for (int di = 0; di < 4; ++di) hn[di][0] = hn[di][1] = 0.f;
            const int cb = 18 + 10 * (4 * f + n);
            #pragma unroll
            for (int c = 0; c < 10; ++c) {
                const float2 xv = *(const float2*)(&xt[(cb + c) * 36 + tb]);
                #pragma unroll
                for (int di = 0; di < 4; ++di) {
                    hn[di][0] = fmaf(wr[c][di], xv.x, hn[di][0]);
                    hn[di][1] = fmaf(wr[c][di], xv.y, hn[di][1]);
                }
            }
            #pragma unroll
            for (int di = 0; di < 4; ++di)
                #pragma unroll
                for (int ti = 0; ti < 2; ++ti) {
                    const float h = hn[di][ti];
                    if (n == 0) {
                        star[di][ti] += h;
                        s12[di][ti] = h;
                        hprev[di][ti] = h;
                    } else if (n == 1) {
                        const float pa = fmaf(cS, h0[di][ti], c3 * (s12[di][ti] + h));
                        pool[di][ti] += fmaxf(pa, 0.f);
                        s12[di][ti] += h;
                        hprev[di][ti] = h;
                    } else if (n == 2) {
                        const float pb = c3 * (s12[di][ti] + h);
                        pool[di][ti] += fmaxf(pb, 0.f);
                        s12[di][ti] = hprev[di][ti] + h;
                        hprev[di][ti] = h;
                    } else {
                        const float pc = fmaf(cT, h, c3 * s12[di][ti]);
                        const float pe = fmaf(cT, hprev[di][ti], cH * h);
                        pool[di][ti] += fmaxf(pc, 0.f) + fmaxf(pe, 0.f);
                    }
                }
        }
    }

    float* hpb = hp + (long)b * 64 * T_LEN + t0 + tb;
    #pragma unroll
    for (int di = 0; di < 4; ++di) {
        float2 r;
        const float p0a = fmaf(cP, h0[di][0], cS * star[di][0]);
        const float p0b = fmaf(cP, h0[di][1], cS * star[di][1]);
        r.x = (pool[di][0] + fmaxf(p0a, 0.f)) * (1.0f / 21.0f);
        r.y = (pool[di][1] + fmaxf(p0b, 0.f)) * (1.0f / 21.0f);
        *(float2*)(hpb + (long)(d0 + di) * T_LEN) = r;
    }
}

// ---------------------------------------------------------------------------
// k_mstcn: one full MSTCN, fused. R10 = R8 structure (128 thr = 8 cjg x
// 16 tt, thread = 4t x 8ch) + DOUBLE-BUFFERED window registers.
// R9 post-mortem: VALUBusy pinned ~40% regardless of occupancy (2 vs 4
// waves/SIMD) -> convoy stall: every wave issues its 9 ds_read_b128 then
// immediately waits lgkmcnt for them; all waves queue on the LDS pipe
// together while VALU idles. Fix: prefetch window for c+1 (winB) while
// computing c (winA) -> 208 FMAs (~416 cyc) of slack cover the ~120 cyc
// LDS latency; ds_reads leave the critical path. Named winA/winB + 2x
// unroll (runtime-indexed reg arrays would spill to scratch).
// ---------------------------------------------------------------------------
template <bool FINAL>
__global__ __launch_bounds__(128) void k_mstcn(
    const float* __restrict__ in,   // [B][64][T]
    const float* __restrict__ ws, const float* __restrict__ bs,
    const float* __restrict__ wm, const float* __restrict__ bm,
    const float* __restrict__ wl, const float* __restrict__ bl,
    const float* __restrict__ wo, const float* __restrict__ bo,
    float* __restrict__ out,        // [B][64][T]  (FINAL=false)
    const float* __restrict__ wd,   // [64][32]    (FINAL=true)
    const float* __restrict__ bd,   // [32]
    float* __restrict__ outp)       // [B][32]     (FINAL=true)
{
    __shared__ float smem[64 * 100]; // x-tile [c][96] stride 100; h aliased

    const int b   = blockIdx.y;
    const int t0  = blockIdx.x * 64;
    const int tid = threadIdx.x;
    const int cjg = tid >> 4;        // 0..7 composite j-group
    const int tt  = tid & 15;        // 4 t at tt*4

    // ---- stage x window [t0-32, t0+64) as [c][96], stride 100 ----
    const float* inb = in + (long)b * 64 * T_LEN;
    #pragma unroll 1
    for (int i = tid; i < 64 * 24; i += 128) {
        const int c = i / 24;
        const int q = i - c * 24;
        const int t = t0 - 32 + q * 4;
        float4 v = make_float4(0.f, 0.f, 0.f, 0.f);
        if (t >= 0) v = *(const float4*)(inb + (long)c * T_LEN + t);
        *(float4*)(&smem[c * 100 + q * 4]) = v;
    }
    __syncthreads();

    // ---- conv phase ----
    const int js = 2 * cjg;          // s channels (concat 0..15)
    const int jm = 2 * cjg;          // m channels (concat 16..31)
    const int jl = 4 * cjg;          // l channels (concat 32..63)

    float as[2][4], am[2][4], al[4][4];
    {
        const float2 b2s = *(const float2*)(bs + js);
        const float2 b2m = *(const float2*)(bm + jm);
        float b4l[4];
        *(float4*)b4l = *(const float4*)(bl + jl);
        #pragma unroll
        for (int i = 0; i < 4; ++i) {
            as[0][i] = b2s.x; as[1][i] = b2s.y;
            am[0][i] = b2m.x; am[1][i] = b2m.y;
            #pragma unroll
            for (int j = 0; j < 4; ++j) al[j][i] = b4l[j];
        }
    }

    float2 wsr[3], wmr[5];
    float  wlr[9][4];
    #pragma unroll
    for (int k = 0; k < 3; ++k) wsr[k] = *(const float2*)(ws + (k * 64) * 16 + js);
    #pragma unroll
    for (int k = 0; k < 5; ++k) wmr[k] = *(const float2*)(wm + (k * 64) * 16 + jm);
    #pragma unroll
    for (int k = 0; k < 9; ++k) *(float4*)wlr[k] = *(const float4*)(wl + (k * 64) * 32 + jl);

    // window double buffer: winA holds current c, winB prefetches c+1
    float winA[36], winB[36];

#define LOADWIN(W, CC) do {                                              \
        const float* rb_ = &smem[(CC) * 100 + tt * 4];                   \
        _Pragma("unroll")                                                \
        for (int m_ = 0; m_ < 9; ++m_)                                   \
            *(float4*)(&(W)[4 * m_]) = *(const float4*)(rb_ + 4 * m_);   \
    } while (0)

#define COMPUTE(W, C) do {                                               \
        const int cn_ = ((C) < 63) ? (C) + 1 : 63;                       \
        _Pragma("unroll")                                                \
        for (int k = 0; k < 3; ++k) {                                    \
            _Pragma("unroll")                                            \
            for (int i = 0; i < 4; ++i) {                                \
                const float v = (W)[30 + i + k];                         \
                as[0][i] = fmaf(wsr[k].x, v, as[0][i]);                  \
                as[1][i] = fmaf(wsr[k].y, v, as[1][i]);                  \
            }                                                            \
            wsr[k] = *(const float2*)(ws + (k * 64 + cn_) * 16 + js);    \
        }                                                                \
        _Pragma("unroll")                                                \
        for (int k = 0; k < 5; ++k) {                                    \
            _Pragma("unroll")                                            \
            for (int i = 0; i < 4; ++i) {                                \
                const float v = (W)[24 + i + 2 * k];                     \
                am[0][i] = fmaf(wmr[k].x, v, am[0][i]);                  \
                am[1][i] = fmaf(wmr[k].y, v, am[1][i]);                  \
            }                                                            \
            wmr[k] = *(const float2*)(wm + (k * 64 + cn_) * 16 + jm);    \
        }                                                                \
        _Pragma("unroll")                                                \
        for (int k = 0; k < 9; ++k) {                                    \
            _Pragma("unroll")                                            \
            for (int i = 0; i < 4; ++i) {                                \
                const float v = (W)[i + 4 * k];                          \
                al[0][i] = fmaf(wlr[k][0], v, al[0][i]);                 \
                al[1][i] = fmaf(wlr[k][1], v, al[1][i]);                 \
                al[2][i] = fmaf(wlr[k][2], v, al[2][i]);                 \
                al[3][i] = fmaf(wlr[k][3], v, al[3][i]);                 \
            }                                                            \
            *(float4*)wlr[k] = *(const float4*)(wl + (k * 64 + cn_) * 32 + jl); \
        }                                                                \
    } while (0)

    LOADWIN(winA, 0);
    #pragma unroll 1
    for (int c = 0; c < 64; c += 2) {
        // prefetch window c+1 into winB, then compute c from winA
        LOADWIN(winB, c + 1);
        COMPUTE(winA, c);
        // prefetch window c+2 into winA (clamped dummy on last iter)
        LOADWIN(winA, (c + 2 < 64) ? c + 2 : 63);
        COMPUTE(winB, c + 1);
    }

#undef LOADWIN
#undef COMPUTE

    // ---- relu + stage h [64 j][64 t] stride 68 (aliased) ----
    __syncthreads();
    #pragma unroll
    for (int j = 0; j < 2; ++j)
        *(float4*)(&smem[(js + j) * 68 + tt * 4]) =
            make_float4(fmaxf(as[j][0], 0.f), fmaxf(as[j][1], 0.f),
                        fmaxf(as[j][2], 0.f), fmaxf(as[j][3], 0.f));
    #pragma unroll
    for (int j = 0; j < 2; ++j)
        *(float4*)(&smem[(16 + jm + j) * 68 + tt * 4]) =
            make_float4(fmaxf(am[j][0], 0.f), fmaxf(am[j][1], 0.f),
                        fmaxf(am[j][2], 0.f), fmaxf(am[j][3], 0.f));
    #pragma unroll
    for (int j = 0; j < 4; ++j)
        *(float4*)(&smem[(32 + jl + j) * 68 + tt * 4]) =
            make_float4(fmaxf(al[j][0], 0.f), fmaxf(al[j][1], 0.f),
                        fmaxf(al[j][2], 0.f), fmaxf(al[j][3], 0.f));
    __syncthreads();

    // ---- conv_out 64->64 (no relu): thread = 8 d x 4 t ----
    const int d0 = cjg * 8;
    float o[8][4];
    {
        float bv[8];
        *(float4*)(&bv[0]) = *(const float4*)(bo + d0);
        *(float4*)(&bv[4]) = *(const float4*)(bo + d0 + 4);
        #pragma unroll
        for (int di = 0; di < 8; ++di)
            #pragma unroll
            for (int i = 0; i < 4; ++i) o[di][i] = bv[di];
    }
    #pragma unroll 4
    for (int j = 0; j < 64; ++j) {
        float wv[8], hv[4];
        *(float4*)(&wv[0]) = *(const float4*)(wo + j * 64 + d0);
        *(float4*)(&wv[4]) = *(const float4*)(wo + j * 64 + d0 + 4);
        *(float4*)hv       = *(const float4*)(&smem[j * 68 + tt * 4]);
        #pragma unroll
        for (int di = 0; di < 8; ++di)
            #pragma unroll
            for (int i = 0; i < 4; ++i)
                o[di][i] = fmaf(wv[di], hv[i], o[di][i]);
    }

    if (!FINAL) {
        float* ob = out + (long)b * 64 * T_LEN + t0 + tt * 4;
        #pragma unroll
        for (int di = 0; di < 8; ++di)
            *(float4*)(ob + (long)(d0 + di) * T_LEN) =
                make_float4(o[di][0], o[di][1], o[di][2], o[di][3]);
    } else {
        // ---- stage t2 [64 d][64 t], then dense 64->32 + tanh + mean ----
        __syncthreads();
        #pragma unroll
        for (int di = 0; di < 8; ++di)
            *(float4*)(&smem[(d0 + di) * 68 + tt * 4]) =
                make_float4(o[di][0], o[di][1], o[di][2], o[di][3]);
        __syncthreads();

        const int eg = tid >> 5;       // 4 groups x 8 e
        const int e0 = eg * 8;
        const int tl = tid & 31;       // 2 t at tl*2
        float fa[8], fb[8];
        *(float4*)(&fa[0]) = *(const float4*)(bd + e0);
        *(float4*)(&fa[4]) = *(const float4*)(bd + e0 + 4);
        #pragma unroll
        for (int e = 0; e < 8; ++e) fb[e] = fa[e];

        #pragma unroll 4
        for (int d = 0; d < 64; ++d) {
            const float2 hv = *(const float2*)(&smem[d * 68 + tl * 2]);
            float wv[8];
            *(float4*)(&wv[0]) = *(const float4*)(wd + d * 32 + e0);
            *(float4*)(&wv[4]) = *(const float4*)(wd + d * 32 + e0 + 4);
            #pragma unroll
            for (int e = 0; e < 8; ++e) {
                fa[e] = fmaf(wv[e], hv.x, fa[e]);
                fb[e] = fmaf(wv[e], hv.y, fb[e]);
            }
        }
        #pragma unroll
        for (int e = 0; e < 8; ++e) {
            float v = (tanhf(fa[e]) + tanhf(fb[e])) * (1.0f / (float)T_LEN);
            v += __shfl_down(v, 16, 32);
            v += __shfl_down(v, 8, 32);
            v += __shfl_down(v, 4, 32);
            v += __shfl_down(v, 2, 32);
            v += __shfl_down(v, 1, 32);
            if (tl == 0) atomicAdd(&outp[b * 32 + e0 + e], v);
        }
    }
}

extern "C" void kernel_launch(void* const* d_in, const int* in_sizes, int n_in,
                              void* d_out, int out_size, void* d_ws, size_t ws_size,
                              hipStream_t stream) {
    const float* x     = (const float*)d_in[0];
    const float* gcn_w = (const float*)d_in[1];
    const float* wd    = (const float*)d_in[2];
    const float* bd    = (const float*)d_in[3];
    const float* t1_ws = (const float*)d_in[4];
    const float* t1_bs = (const float*)d_in[5];
    const float* t1_wm = (const float*)d_in[6];
    const float* t1_bm = (const float*)d_in[7];
    const float* t1_wl = (const float*)d_in[8];
    const float* t1_bl = (const float*)d_in[9];
    const float* t1_wo = (const float*)d_in[10];
    const float* t1_bo = (const float*)d_in[11];
    const float* t2_ws = (const float*)d_in[12];
    const float* t2_bs = (const float*)d_in[13];
    const float* t2_wm = (const float*)d_in[14];
    const float* t2_bm = (const float*)d_in[15];
    const float* t2_wl = (const float*)d_in[16];
    const float* t2_bl = (const float*)d_in[17];
    const float* t2_wo = (const float*)d_in[18];
    const float* t2_bo = (const float*)d_in[19];

    float* b0 = (float*)d_ws;                          // [16][64][4096]
    float* b1 = b0 + (size_t)BATCH * 64 * T_LEN;       // [16][64][4096]

    hipMemsetAsync(d_out, 0, (size_t)out_size * sizeof(float), stream);

    k_gcn<<<dim3(T_LEN / 32, BATCH), 256, 0, stream>>>(x, gcn_w, b0);

    k_mstcn<false><<<dim3(T_LEN / 64, BATCH), 128, 0, stream>>>(
        b0, t1_ws, t1_bs, t1_wm, t1_bm, t1_wl, t1_bl, t1_wo, t1_bo,
        b1, nullptr, nullptr, nullptr);

    k_mstcn<true><<<dim3(T_LEN / 64, BATCH), 128, 0, stream>>>(
        b1, t2_ws, t2_bs, t2_wm, t2_bm, t2_wl, t2_bl, t2_wo, t2_bo,
        nullptr, wd, bd, (float*)d_out);
}